// Round 8
// baseline (571.186 us; speedup 1.0000x reference)
//
#include <hip/hip_runtime.h>
#include <hip/hip_bf16.h>

typedef __attribute__((ext_vector_type(8))) short short8;
typedef __attribute__((ext_vector_type(4))) float f32x4;

#define BB 8
#define NN 32768
#define KK 128
#define DD 64
#define TAU 1.0f
#define ITERS 10
#define EPSV 1e-8f
#define JPARTS 128

// ---- d_out layout (floats) ----
#define G_SZ   ((size_t)BB * NN * KK)
#define PI_OFF (G_SZ)
#define XY_OFF (PI_OFF + (size_t)BB * KK)
#define NF_OUT (XY_OFF + (size_t)BB * KK * 3)

// ---- d_ws layout (floats) ----
#define SLICE_F (BB * KK * 4)                        // 4096
#define CT_OFF  ((ITERS + 1) * SLICE_F)              // 45056: transformed centers x11
#define SS_OFF  (CT_OFF + (ITERS + 1) * SLICE_F)     // 90112: s_sum (8)
#define CNT_OFF (SS_OFF + 8)                         // 10 int counters
#define HDR_F   (SS_OFF + 24)                        // 90136 (16B aligned)
#define PART_OFF HDR_F
#define PART_F  ((size_t)JPARTS * BB * KK * DD)
#define WS_NEED_BYTES  ((PART_OFF + PART_F) * 4)

__device__ __forceinline__ unsigned pk2(float a, float b) {
    __hip_bfloat162 h = __float22bfloat162_rn(make_float2(a, b));
    unsigned u; __builtin_memcpy(&u, &h, 4); return u;
}

// ================= prep: s_sum + transformed initial centers cT[0] ==============
__global__ __launch_bounds__(256) void prep_kernel(const float* __restrict__ xyz,
                                                   const float* __restrict__ sc,
                                                   float* __restrict__ ws) {
    int b = blockIdx.x, tid = threadIdx.x, wave = tid >> 6, lane = tid & 63;
    const float* S = sc + (size_t)b * NN;
    float sum = 0.f;
    for (int i = tid; i < NN; i += 256) sum += S[i];
    #pragma unroll
    for (int m = 1; m <= 32; m <<= 1) sum += __shfl_xor(sum, m, 64);
    __shared__ float red[4];
    if (lane == 0) red[wave] = sum;
    __syncthreads();
    if (tid == 0) ws[SS_OFF + b] = red[0] + red[1] + red[2] + red[3] + EPSV;
    if (tid < KK) {
        const float* X = xyz + (size_t)b * 3 * NN;
        int i0 = tid * (NN / KK);
        float cx = X[i0], cy = X[NN + i0], cz = X[2 * NN + i0];
        ((float4*)(ws + CT_OFF))[b * KK + tid] =
            make_float4(2.f * cx / TAU, 2.f * cy / TAU, 2.f * cz / TAU,
                        -(cx * cx + cy * cy + cz * cz) / TAU);
    }
}

// ============ assign: scalar-load pass1, reg-center pass2, finisher transform ===
// grid (64, B), block 256, 512 points/block.
template <bool LAST>
__global__ __launch_bounds__(256) void assign_kernel(
    const float* __restrict__ xyz, const float* __restrict__ sc,
    const float4* __restrict__ cT_in,   // transformed centers, iteration it
    float* __restrict__ accOut,         // acc slice it+1 base (all batches, zeroed)
    float4* __restrict__ cT_out,        // transformed centers, iteration it+1
    int* __restrict__ counter,          // zeroed per launch
    float* __restrict__ gamma_out)
{
    __shared__ float4 wLds[512];     // {x,y,z, s/l}
    __shared__ float  accW[4][512];
    __shared__ int lastFlag;

    const int b = blockIdx.y, blk = blockIdx.x;
    const int tid = threadIdx.x, wave = tid >> 6, lane = tid & 63;

    const float* X = xyz + (size_t)b * 3 * NN;
    const float* S = sc + (size_t)b * NN;

    const int n = blk * 512 + tid;
    const float px0 = X[n],       py0 = X[NN + n],       pz0 = X[2 * NN + n],       ps0 = S[n];
    const float px1 = X[n + 256], py1 = X[NN + n + 256], pz1 = X[2 * NN + n + 256], ps1 = S[n + 256];

    // pass-2 centers: per-lane coalesced loads, issued early (latency hidden by pass1)
    const float4 c0 = cT_in[b * KK + lane];
    const float4 c1 = cT_in[b * KK + lane + 64];

    // pass 1: wave-uniform center index -> s_load_dwordx4 (scalar cache), no LDS
    float l0a = 0.f, l0b = 0.f, l1a = 0.f, l1b = 0.f;
    #pragma unroll 8
    for (int k = 0; k < KK; k += 2) {
        float4 ca = cT_in[b * KK + k];
        float4 cb = cT_in[b * KK + k + 1];
        l0a += __expf(fmaf(px0, ca.x, fmaf(py0, ca.y, fmaf(pz0, ca.z, ca.w))));
        l1a += __expf(fmaf(px1, ca.x, fmaf(py1, ca.y, fmaf(pz1, ca.z, ca.w))));
        l0b += __expf(fmaf(px0, cb.x, fmaf(py0, cb.y, fmaf(pz0, cb.z, cb.w))));
        l1b += __expf(fmaf(px1, cb.x, fmaf(py1, cb.y, fmaf(pz1, cb.z, cb.w))));
    }
    wLds[tid]       = make_float4(px0, py0, pz0, ps0 / (l0a + l0b));
    wLds[tid + 256] = make_float4(px1, py1, pz1, ps1 / (l1a + l1b));
    __syncthreads();

    // pass 2: lane owns clusters lane, lane+64; wave sweeps its 128 points.
    float ax0 = 0, ay0 = 0, az0 = 0, aw0 = 0;
    float ax1 = 0, ay1 = 0, az1 = 0, aw1 = 0;
    float* grow = gamma_out + ((size_t)b * NN + blk * 512 + (wave << 7)) * KK + lane;

    #pragma unroll 4
    for (int j = 0; j < 128; ++j) {
        float4 P = wLds[(wave << 7) | j];   // wave-uniform broadcast
        float g0 = __expf(fmaf(P.x, c0.x, fmaf(P.y, c0.y, fmaf(P.z, c0.z, c0.w)))) * P.w;
        float g1 = __expf(fmaf(P.x, c1.x, fmaf(P.y, c1.y, fmaf(P.z, c1.z, c1.w)))) * P.w;
        if (LAST) {
            grow[(size_t)j * KK] = g0;
            grow[(size_t)j * KK + 64] = g1;
        }
        ax0 = fmaf(g0, P.x, ax0); ay0 = fmaf(g0, P.y, ay0);
        az0 = fmaf(g0, P.z, az0); aw0 += g0;
        ax1 = fmaf(g1, P.x, ax1); ay1 = fmaf(g1, P.y, ay1);
        az1 = fmaf(g1, P.z, az1); aw1 += g1;
    }

    ((float4*)accW[wave])[lane]      = make_float4(ax0, ay0, az0, aw0);
    ((float4*)accW[wave])[lane + 64] = make_float4(ax1, ay1, az1, aw1);
    __syncthreads();
    float v0 = accW[0][tid]       + accW[1][tid]       + accW[2][tid]       + accW[3][tid];
    float v1 = accW[0][tid + 256] + accW[1][tid + 256] + accW[2][tid + 256] + accW[3][tid + 256];
    float* ag = accOut + b * (KK * 4);
    atomicAdd(ag + tid, v0);
    atomicAdd(ag + tid + 256, v1);

    // ---- last-finishing block transforms acc -> cT_out for the next iteration
    __threadfence();
    if (tid == 0)
        lastFlag = (atomicAdd(counter, 1) == (int)(gridDim.x * gridDim.y) - 1);
    __syncthreads();
    if (lastFlag) {
        for (int i = tid; i < BB * KK; i += 256) {
            const float* a = accOut + 4 * i;
            float ax = __hip_atomic_load(a + 0, __ATOMIC_RELAXED, __HIP_MEMORY_SCOPE_AGENT);
            float ay = __hip_atomic_load(a + 1, __ATOMIC_RELAXED, __HIP_MEMORY_SCOPE_AGENT);
            float az = __hip_atomic_load(a + 2, __ATOMIC_RELAXED, __HIP_MEMORY_SCOPE_AGENT);
            float aw = __hip_atomic_load(a + 3, __ATOMIC_RELAXED, __HIP_MEMORY_SCOPE_AGENT);
            float denom = aw + EPSV;
            float cx = ax / denom, cy = ay / denom, cz = az / denom;
            cT_out[i] = make_float4(2.f * cx / TAU, 2.f * cy / TAU, 2.f * cz / TAU,
                                    -(cx * cx + cy * cy + cz * cz) / TAU);
        }
    }
}

// ================= final: node_xyz + pi from slice ITERS =================
__global__ void final_kernel(const float* __restrict__ ws, float* __restrict__ out) {
    int b = blockIdx.x, k = threadIdx.x;
    float4 a = ((const float4*)(ws + ITERS * SLICE_F))[b * KK + k];
    float denom = a.w + EPSV;
    float* oxyz = out + XY_OFF + (size_t)(b * KK + k) * 3;
    oxyz[0] = a.x / denom; oxyz[1] = a.y / denom; oxyz[2] = a.z / denom;
    out[PI_OFF + b * KK + k] = a.w / ws[SS_OFF + b];
}

// ====== nf_mfma2: partial nf[k][d] via 16x16x32 bf16 MFMA (round-6 proven) =====
__global__ __launch_bounds__(256) void nf_mfma2(const float* __restrict__ gamma,
                                                const float* __restrict__ feats,
                                                float* __restrict__ dst) {
    __shared__ unsigned short gT[KK * 40];   // [k][pitch 40 bf16], 10240 B
    const int b = blockIdx.y, part = blockIdx.x;
    const int tid = threadIdx.x, wave = tid >> 6, lane = tid & 63;
    const int r = lane & 15, hi = lane >> 4;
    const int p = tid & 15, q0 = tid >> 4;

    f32x4 acc[2][4];
    #pragma unroll
    for (int kt = 0; kt < 2; kt++)
        #pragma unroll
        for (int dt = 0; dt < 4; dt++) acc[kt][dt] = (f32x4){0.f, 0.f, 0.f, 0.f};

    const float* gb = gamma + (size_t)b * NN * KK + (size_t)part * 256 * KK;
    const float* fb = feats + (size_t)b * DD * NN;
    const int n0 = part * 256;

    for (int ch = 0; ch < 8; ++ch) {
        const float* gr0 = gb + (size_t)(ch * 32 + 2 * p) * KK;
        const float* gr1 = gr0 + KK;
        unsigned* rowd = (unsigned*)gT;
        #pragma unroll
        for (int s = 0; s < 2; ++s) {
            int q = q0 + 16 * s;
            float4 x = *(const float4*)(gr0 + 4 * q);
            float4 y = *(const float4*)(gr1 + 4 * q);
            rowd[(4 * q + 0) * 20 + p] = pk2(x.x, y.x);
            rowd[(4 * q + 1) * 20 + p] = pk2(x.y, y.y);
            rowd[(4 * q + 2) * 20 + p] = pk2(x.z, y.z);
            rowd[(4 * q + 3) * 20 + p] = pk2(x.w, y.w);
        }
        __syncthreads();

        const unsigned short* a0p = gT + (wave * 32 + r) * 40 + hi * 8;
        short8 a0 = *(const short8*)a0p;
        short8 a1 = *(const short8*)(a0p + 16 * 40);
        const int nn = n0 + ch * 32 + hi * 8;
        #pragma unroll
        for (int dt = 0; dt < 4; ++dt) {
            const float* fr = fb + (size_t)(dt * 16 + r) * NN + nn;
            float4 x = *(const float4*)fr;
            float4 y = *(const float4*)(fr + 4);
            union { unsigned u[4]; short8 s; } bu;
            bu.u[0] = pk2(x.x, x.y); bu.u[1] = pk2(x.z, x.w);
            bu.u[2] = pk2(y.x, y.y); bu.u[3] = pk2(y.z, y.w);
            acc[0][dt] = __builtin_amdgcn_mfma_f32_16x16x32_bf16(a0, bu.s, acc[0][dt], 0, 0, 0);
            acc[1][dt] = __builtin_amdgcn_mfma_f32_16x16x32_bf16(a1, bu.s, acc[1][dt], 0, 0, 0);
        }
        __syncthreads();
    }

    float* pdst = dst + ((size_t)(b * JPARTS + part)) * (KK * DD) + (size_t)(wave * 32) * DD;
    #pragma unroll
    for (int kt = 0; kt < 2; kt++)
        #pragma unroll
        for (int dt = 0; dt < 4; dt++)
            #pragma unroll
            for (int rr = 0; rr < 4; rr++)
                pdst[(kt * 16 + hi * 4 + rr) * DD + dt * 16 + r] = acc[kt][dt][rr];
}

// ====== fallback f32 nf_compute (round-4 proven), atomic variant ======
__global__ __launch_bounds__(256) void nf_compute_atomic(const float* __restrict__ gamma,
                                                         const float* __restrict__ feats,
                                                         float* __restrict__ dst) {
    __shared__ float gLds[32 * 128];
    __shared__ float fLds[64 * 33];
    const int b = blockIdx.y, part = blockIdx.x, tid = threadIdx.x;
    const int kq = (tid & 15) * 8, dg = (tid >> 4) * 4;
    float acc[8][4];
    #pragma unroll
    for (int i = 0; i < 8; i++)
        #pragma unroll
        for (int u = 0; u < 4; u++) acc[i][u] = 0.f;
    const float* gb = gamma + (size_t)b * NN * KK + (size_t)part * (NN / JPARTS) * KK;
    const float* fb = feats + (size_t)b * DD * NN + part * (NN / JPARTS);
    for (int ch = 0; ch < (NN / JPARTS) / 32; ++ch) {
        const float4* gs = (const float4*)(gb + (size_t)ch * 32 * KK);
        #pragma unroll
        for (int i = 0; i < 4; i++) ((float4*)gLds)[tid + i * 256] = gs[tid + i * 256];
        #pragma unroll
        for (int i = 0; i < 2; i++) {
            int idx = tid + i * 256;
            int d = idx >> 3, c4 = (idx & 7) * 4;
            float4 fv = *(const float4*)(fb + (size_t)d * NN + ch * 32 + c4);
            float* fr = &fLds[d * 33 + c4];
            fr[0] = fv.x; fr[1] = fv.y; fr[2] = fv.z; fr[3] = fv.w;
        }
        __syncthreads();
        #pragma unroll 4
        for (int nl = 0; nl < 32; ++nl) {
            float4 g0 = *(const float4*)&gLds[nl * 128 + kq];
            float4 g1 = *(const float4*)&gLds[nl * 128 + kq + 4];
            float fv[4];
            #pragma unroll
            for (int u = 0; u < 4; u++) fv[u] = fLds[(dg + u) * 33 + nl];
            float gk[8] = {g0.x, g0.y, g0.z, g0.w, g1.x, g1.y, g1.z, g1.w};
            #pragma unroll
            for (int i = 0; i < 8; i++)
                #pragma unroll
                for (int u = 0; u < 4; u++)
                    acc[i][u] = fmaf(gk[i], fv[u], acc[i][u]);
        }
        __syncthreads();
    }
    float* nf = dst + (size_t)b * KK * DD;
    #pragma unroll
    for (int i = 0; i < 8; i++)
        #pragma unroll
        for (int u = 0; u < 4; u++)
            atomicAdd(&nf[(kq + i) * DD + dg + u], acc[i][u]);
}

// ====== nf_reduce: sum JPARTS partials, divide by denom, write out ======
__global__ __launch_bounds__(256) void nf_reduce(const float* __restrict__ ws,
                                                 float* __restrict__ out) {
    int idx = blockIdx.x * 256 + threadIdx.x;
    int b = idx >> 13, e = idx & 8191;
    const float* p = ws + PART_OFF + (size_t)b * JPARTS * (KK * DD) + e;
    float sum = 0.f;
    #pragma unroll 8
    for (int j = 0; j < JPARTS; ++j) sum += p[(size_t)j * (KK * DD)];
    int k = e >> 6;
    float denom = ws[ITERS * SLICE_F + (b * KK + k) * 4 + 3] + EPSV;
    out[NF_OUT + idx] = sum / denom;
}

__global__ __launch_bounds__(256) void nf_finalize(const float* __restrict__ ws,
                                                   float* __restrict__ out) {
    int idx = blockIdx.x * 256 + threadIdx.x;
    int bk = idx / DD;
    float denom = ws[ITERS * SLICE_F + bk * 4 + 3] + EPSV;
    out[NF_OUT + idx] = out[NF_OUT + idx] / denom;
}

extern "C" void kernel_launch(void* const* d_in, const int* in_sizes, int n_in,
                              void* d_out, int out_size, void* d_ws, size_t ws_size,
                              hipStream_t stream) {
    const float* xyz = (const float*)d_in[0];
    const float* feats = (const float*)d_in[1];
    const float* sc = (const float*)d_in[2];
    float* out = (float*)d_out;
    float* ws = (float*)d_ws;
    int* cnt = (int*)(ws + CNT_OFF);

    hipMemsetAsync(ws, 0, (size_t)HDR_F * sizeof(float), stream);
    prep_kernel<<<BB, 256, 0, stream>>>(xyz, sc, ws);

    for (int it = 0; it < ITERS; it++) {
        const float4* cT_in = (const float4*)(ws + CT_OFF + it * SLICE_F);
        float4* cT_out = (float4*)(ws + CT_OFF + (it + 1) * SLICE_F);
        float* accOut = ws + (it + 1) * SLICE_F;
        if (it < ITERS - 1)
            assign_kernel<false><<<dim3(64, BB), 256, 0, stream>>>(
                xyz, sc, cT_in, accOut, cT_out, cnt + it, out);
        else
            assign_kernel<true><<<dim3(64, BB), 256, 0, stream>>>(
                xyz, sc, cT_in, accOut, cT_out, cnt + it, out);
    }

    final_kernel<<<BB, KK, 0, stream>>>(ws, out);

    if (ws_size >= WS_NEED_BYTES) {
        nf_mfma2<<<dim3(JPARTS, BB), 256, 0, stream>>>(out, feats, ws + PART_OFF);
        nf_reduce<<<256, 256, 0, stream>>>(ws, out);
    } else {
        hipMemsetAsync(out + NF_OUT, 0, (size_t)BB * KK * DD * sizeof(float), stream);
        nf_compute_atomic<<<dim3(JPARTS, BB), 256, 0, stream>>>(out, feats, out + NF_OUT);
        nf_finalize<<<256, 256, 0, stream>>>(ws, out);
    }
}

// Round 9
// 358.540 us; speedup vs baseline: 1.5931x; 1.5931x over previous
//
#include <hip/hip_runtime.h>
#include <hip/hip_bf16.h>

typedef __attribute__((ext_vector_type(8))) short short8;
typedef __attribute__((ext_vector_type(4))) float f32x4;

#define BB 8
#define NN 32768
#define KK 128
#define DD 64
#define TAU 1.0f
#define ITERS 10
#define EPSV 1e-8f
#define JPARTS 128

// ---- d_out layout (floats) ----
#define G_SZ   ((size_t)BB * NN * KK)
#define PI_OFF (G_SZ)
#define XY_OFF (PI_OFF + (size_t)BB * KK)
#define NF_OUT (XY_OFF + (size_t)BB * KK * 3)

// ---- d_ws layout (floats) ----  (round-7 layout)
#define SLICE_F (BB * KK * 4)                  // 4096
#define SS_OFF  ((ITERS + 1) * SLICE_F)        // 45056
#define HDR_F   (SS_OFF + 16)                  // 45072
#define PART_OFF HDR_F
#define PART_F  ((size_t)JPARTS * BB * KK * DD)
#define WS_NEED_BYTES  ((PART_OFF + PART_F) * 4)

__device__ __forceinline__ unsigned pk2(float a, float b) {
    __hip_bfloat162 h = __float22bfloat162_rn(make_float2(a, b));
    unsigned u; __builtin_memcpy(&u, &h, 4); return u;
}
__device__ __forceinline__ float rdl(float v, int l) {
    return __int_as_float(__builtin_amdgcn_readlane(__float_as_int(v), l));
}

// ================= prep: s_sum + initial centers as acc slice 0 =================
__global__ __launch_bounds__(256) void prep_kernel(const float* __restrict__ xyz,
                                                   const float* __restrict__ sc,
                                                   float* __restrict__ ws) {
    int b = blockIdx.x, tid = threadIdx.x, wave = tid >> 6, lane = tid & 63;
    const float* S = sc + (size_t)b * NN;
    float sum = 0.f;
    for (int i = tid; i < NN; i += 256) sum += S[i];
    #pragma unroll
    for (int m = 1; m <= 32; m <<= 1) sum += __shfl_xor(sum, m, 64);
    __shared__ float red[4];
    if (lane == 0) red[wave] = sum;
    __syncthreads();
    if (tid == 0) ws[SS_OFF + b] = red[0] + red[1] + red[2] + red[3] + EPSV;
    if (tid < KK) {
        const float* X = xyz + (size_t)b * 3 * NN;
        int i0 = tid * (NN / KK);
        ((float4*)ws)[b * KK + tid] =
            make_float4(X[i0], X[NN + i0], X[2 * NN + i0], 1.0f);
    }
}

// ============ assign: LDS-free hot loops via v_readlane broadcasts ==============
// grid (64, B), block 256 (4 waves), 512 points/block.
// Wave w owns points [blk*512 + w*128, +128): lane holds P0 (=pt w*128+lane) and
// P1 (=pt w*128+64+lane). Lane also owns clusters lane, lane+64 (c0, c1 computed
// in-register from accIn). Pass1 broadcasts centers, pass2 broadcasts points —
// all via readlane (register file), LDS used only for the 8KB accW reduce.
template <bool LAST>
__global__ __launch_bounds__(256) void assign_kernel(
    const float* __restrict__ xyz, const float* __restrict__ sc,
    const float4* __restrict__ accIn,   // slice it
    float* __restrict__ accOut,         // slice it+1 (pre-zeroed)
    float* __restrict__ gamma_out)
{
    __shared__ float accW[4][512];

    const int b = blockIdx.y, blk = blockIdx.x;
    const int tid = threadIdx.x, wave = tid >> 6, lane = tid & 63;

    const float* X = xyz + (size_t)b * 3 * NN;
    const float* S = sc + (size_t)b * NN;

    const int n0 = blk * 512 + (wave << 7) + lane;    // P0 index
    const float px0 = X[n0],      py0 = X[NN + n0],      pz0 = X[2 * NN + n0],      ps0 = S[n0];
    const float px1 = X[n0 + 64], py1 = X[NN + n0 + 64], pz1 = X[2 * NN + n0 + 64], ps1 = S[n0 + 64];

    // per-lane transformed centers (clusters lane, lane+64) from accumulator
    float4 a0 = accIn[b * KK + lane];
    float4 a1 = accIn[b * KK + 64 + lane];
    float d0 = a0.w + EPSV, d1 = a1.w + EPSV;
    float cx0 = a0.x / d0, cy0 = a0.y / d0, cz0 = a0.z / d0;
    float cx1 = a1.x / d1, cy1 = a1.y / d1, cz1 = a1.z / d1;
    const float4 c0 = make_float4(2.f * cx0 / TAU, 2.f * cy0 / TAU, 2.f * cz0 / TAU,
                                  -(cx0 * cx0 + cy0 * cy0 + cz0 * cz0) / TAU);
    const float4 c1 = make_float4(2.f * cx1 / TAU, 2.f * cy1 / TAU, 2.f * cz1 / TAU,
                                  -(cx1 * cx1 + cy1 * cy1 + cz1 * cz1) / TAU);

    // pass 1: softmax denominators for own 2 points; centers via readlane
    float l0 = 0.f, l1 = 0.f;
    #pragma unroll 8
    for (int k = 0; k < 64; ++k) {
        float cx = rdl(c0.x, k), cy = rdl(c0.y, k), cz = rdl(c0.z, k), cw = rdl(c0.w, k);
        l0 += __expf(fmaf(px0, cx, fmaf(py0, cy, fmaf(pz0, cz, cw))));
        l1 += __expf(fmaf(px1, cx, fmaf(py1, cy, fmaf(pz1, cz, cw))));
    }
    #pragma unroll 8
    for (int k = 0; k < 64; ++k) {
        float cx = rdl(c1.x, k), cy = rdl(c1.y, k), cz = rdl(c1.z, k), cw = rdl(c1.w, k);
        l0 += __expf(fmaf(px0, cx, fmaf(py0, cy, fmaf(pz0, cz, cw))));
        l1 += __expf(fmaf(px1, cx, fmaf(py1, cy, fmaf(pz1, cz, cw))));
    }
    const float w0 = ps0 / l0, w1 = ps1 / l1;

    // pass 2: sweep own wave's 128 points via readlane; lane owns clusters lane,lane+64
    float ax0 = 0, ay0 = 0, az0 = 0, aw0 = 0;
    float ax1 = 0, ay1 = 0, az1 = 0, aw1 = 0;
    float* grow = gamma_out + ((size_t)b * NN + blk * 512 + (wave << 7)) * KK + lane;

    #pragma unroll 8
    for (int j = 0; j < 64; ++j) {
        float qx = rdl(px0, j), qy = rdl(py0, j), qz = rdl(pz0, j), qw = rdl(w0, j);
        float g0 = __expf(fmaf(qx, c0.x, fmaf(qy, c0.y, fmaf(qz, c0.z, c0.w)))) * qw;
        float g1 = __expf(fmaf(qx, c1.x, fmaf(qy, c1.y, fmaf(qz, c1.z, c1.w)))) * qw;
        if (LAST) {
            grow[(size_t)j * KK] = g0;
            grow[(size_t)j * KK + 64] = g1;
        }
        ax0 = fmaf(g0, qx, ax0); ay0 = fmaf(g0, qy, ay0);
        az0 = fmaf(g0, qz, az0); aw0 += g0;
        ax1 = fmaf(g1, qx, ax1); ay1 = fmaf(g1, qy, ay1);
        az1 = fmaf(g1, qz, az1); aw1 += g1;
    }
    #pragma unroll 8
    for (int j = 0; j < 64; ++j) {
        float qx = rdl(px1, j), qy = rdl(py1, j), qz = rdl(pz1, j), qw = rdl(w1, j);
        float g0 = __expf(fmaf(qx, c0.x, fmaf(qy, c0.y, fmaf(qz, c0.z, c0.w)))) * qw;
        float g1 = __expf(fmaf(qx, c1.x, fmaf(qy, c1.y, fmaf(qz, c1.z, c1.w)))) * qw;
        if (LAST) {
            grow[(size_t)(j + 64) * KK] = g0;
            grow[(size_t)(j + 64) * KK + 64] = g1;
        }
        ax0 = fmaf(g0, qx, ax0); ay0 = fmaf(g0, qy, ay0);
        az0 = fmaf(g0, qz, az0); aw0 += g0;
        ax1 = fmaf(g1, qx, ax1); ay1 = fmaf(g1, qy, ay1);
        az1 = fmaf(g1, qz, az1); aw1 += g1;
    }

    ((float4*)accW[wave])[lane]      = make_float4(ax0, ay0, az0, aw0);
    ((float4*)accW[wave])[lane + 64] = make_float4(ax1, ay1, az1, aw1);
    __syncthreads();
    float v0 = accW[0][tid]       + accW[1][tid]       + accW[2][tid]       + accW[3][tid];
    float v1 = accW[0][tid + 256] + accW[1][tid + 256] + accW[2][tid + 256] + accW[3][tid + 256];
    float* ag = accOut + b * (KK * 4);
    atomicAdd(ag + tid, v0);
    atomicAdd(ag + tid + 256, v1);
}

// ================= final: node_xyz + pi from slice ITERS =================
__global__ void final_kernel(const float* __restrict__ ws, float* __restrict__ out) {
    int b = blockIdx.x, k = threadIdx.x;
    float4 a = ((const float4*)(ws + ITERS * SLICE_F))[b * KK + k];
    float denom = a.w + EPSV;
    float* oxyz = out + XY_OFF + (size_t)(b * KK + k) * 3;
    oxyz[0] = a.x / denom; oxyz[1] = a.y / denom; oxyz[2] = a.z / denom;
    out[PI_OFF + b * KK + k] = a.w / ws[SS_OFF + b];
}

// ====== nf_mfma2: partial nf[k][d] via 16x16x32 bf16 MFMA (round-6 proven) =====
__global__ __launch_bounds__(256) void nf_mfma2(const float* __restrict__ gamma,
                                                const float* __restrict__ feats,
                                                float* __restrict__ dst) {
    __shared__ unsigned short gT[KK * 40];   // [k][pitch 40 bf16], 10240 B
    const int b = blockIdx.y, part = blockIdx.x;
    const int tid = threadIdx.x, wave = tid >> 6, lane = tid & 63;
    const int r = lane & 15, hi = lane >> 4;
    const int p = tid & 15, q0 = tid >> 4;

    f32x4 acc[2][4];
    #pragma unroll
    for (int kt = 0; kt < 2; kt++)
        #pragma unroll
        for (int dt = 0; dt < 4; dt++) acc[kt][dt] = (f32x4){0.f, 0.f, 0.f, 0.f};

    const float* gb = gamma + (size_t)b * NN * KK + (size_t)part * 256 * KK;
    const float* fb = feats + (size_t)b * DD * NN;
    const int n0 = part * 256;

    for (int ch = 0; ch < 8; ++ch) {
        const float* gr0 = gb + (size_t)(ch * 32 + 2 * p) * KK;
        const float* gr1 = gr0 + KK;
        unsigned* rowd = (unsigned*)gT;
        #pragma unroll
        for (int s = 0; s < 2; ++s) {
            int q = q0 + 16 * s;
            float4 x = *(const float4*)(gr0 + 4 * q);
            float4 y = *(const float4*)(gr1 + 4 * q);
            rowd[(4 * q + 0) * 20 + p] = pk2(x.x, y.x);
            rowd[(4 * q + 1) * 20 + p] = pk2(x.y, y.y);
            rowd[(4 * q + 2) * 20 + p] = pk2(x.z, y.z);
            rowd[(4 * q + 3) * 20 + p] = pk2(x.w, y.w);
        }
        __syncthreads();

        const unsigned short* a0p = gT + (wave * 32 + r) * 40 + hi * 8;
        short8 a0 = *(const short8*)a0p;
        short8 a1 = *(const short8*)(a0p + 16 * 40);
        const int nn = n0 + ch * 32 + hi * 8;
        #pragma unroll
        for (int dt = 0; dt < 4; ++dt) {
            const float* fr = fb + (size_t)(dt * 16 + r) * NN + nn;
            float4 x = *(const float4*)fr;
            float4 y = *(const float4*)(fr + 4);
            union { unsigned u[4]; short8 s; } bu;
            bu.u[0] = pk2(x.x, x.y); bu.u[1] = pk2(x.z, x.w);
            bu.u[2] = pk2(y.x, y.y); bu.u[3] = pk2(y.z, y.w);
            acc[0][dt] = __builtin_amdgcn_mfma_f32_16x16x32_bf16(a0, bu.s, acc[0][dt], 0, 0, 0);
            acc[1][dt] = __builtin_amdgcn_mfma_f32_16x16x32_bf16(a1, bu.s, acc[1][dt], 0, 0, 0);
        }
        __syncthreads();
    }

    float* pdst = dst + ((size_t)(b * JPARTS + part)) * (KK * DD) + (size_t)(wave * 32) * DD;
    #pragma unroll
    for (int kt = 0; kt < 2; kt++)
        #pragma unroll
        for (int dt = 0; dt < 4; dt++)
            #pragma unroll
            for (int rr = 0; rr < 4; rr++)
                pdst[(kt * 16 + hi * 4 + rr) * DD + dt * 16 + r] = acc[kt][dt][rr];
}

// ====== fallback f32 nf_compute (round-4 proven), atomic variant ======
__global__ __launch_bounds__(256) void nf_compute_atomic(const float* __restrict__ gamma,
                                                         const float* __restrict__ feats,
                                                         float* __restrict__ dst) {
    __shared__ float gLds[32 * 128];
    __shared__ float fLds[64 * 33];
    const int b = blockIdx.y, part = blockIdx.x, tid = threadIdx.x;
    const int kq = (tid & 15) * 8, dg = (tid >> 4) * 4;
    float acc[8][4];
    #pragma unroll
    for (int i = 0; i < 8; i++)
        #pragma unroll
        for (int u = 0; u < 4; u++) acc[i][u] = 0.f;
    const float* gb = gamma + (size_t)b * NN * KK + (size_t)part * (NN / JPARTS) * KK;
    const float* fb = feats + (size_t)b * DD * NN + part * (NN / JPARTS);
    for (int ch = 0; ch < (NN / JPARTS) / 32; ++ch) {
        const float4* gs = (const float4*)(gb + (size_t)ch * 32 * KK);
        #pragma unroll
        for (int i = 0; i < 4; i++) ((float4*)gLds)[tid + i * 256] = gs[tid + i * 256];
        #pragma unroll
        for (int i = 0; i < 2; i++) {
            int idx = tid + i * 256;
            int d = idx >> 3, c4 = (idx & 7) * 4;
            float4 fv = *(const float4*)(fb + (size_t)d * NN + ch * 32 + c4);
            float* fr = &fLds[d * 33 + c4];
            fr[0] = fv.x; fr[1] = fv.y; fr[2] = fv.z; fr[3] = fv.w;
        }
        __syncthreads();
        #pragma unroll 4
        for (int nl = 0; nl < 32; ++nl) {
            float4 g0 = *(const float4*)&gLds[nl * 128 + kq];
            float4 g1 = *(const float4*)&gLds[nl * 128 + kq + 4];
            float fv[4];
            #pragma unroll
            for (int u = 0; u < 4; u++) fv[u] = fLds[(dg + u) * 33 + nl];
            float gk[8] = {g0.x, g0.y, g0.z, g0.w, g1.x, g1.y, g1.z, g1.w};
            #pragma unroll
            for (int i = 0; i < 8; i++)
                #pragma unroll
                for (int u = 0; u < 4; u++)
                    acc[i][u] = fmaf(gk[i], fv[u], acc[i][u]);
        }
        __syncthreads();
    }
    float* nf = dst + (size_t)b * KK * DD;
    #pragma unroll
    for (int i = 0; i < 8; i++)
        #pragma unroll
        for (int u = 0; u < 4; u++)
            atomicAdd(&nf[(kq + i) * DD + dg + u], acc[i][u]);
}

// ====== nf_reduce: sum JPARTS partials, divide by denom, write out ======
__global__ __launch_bounds__(256) void nf_reduce(const float* __restrict__ ws,
                                                 float* __restrict__ out) {
    int idx = blockIdx.x * 256 + threadIdx.x;
    int b = idx >> 13, e = idx & 8191;
    const float* p = ws + PART_OFF + (size_t)b * JPARTS * (KK * DD) + e;
    float sum = 0.f;
    #pragma unroll 8
    for (int j = 0; j < JPARTS; ++j) sum += p[(size_t)j * (KK * DD)];
    int k = e >> 6;
    float denom = ws[ITERS * SLICE_F + (b * KK + k) * 4 + 3] + EPSV;
    out[NF_OUT + idx] = sum / denom;
}

__global__ __launch_bounds__(256) void nf_finalize(const float* __restrict__ ws,
                                                   float* __restrict__ out) {
    int idx = blockIdx.x * 256 + threadIdx.x;
    int bk = idx / DD;
    float denom = ws[ITERS * SLICE_F + bk * 4 + 3] + EPSV;
    out[NF_OUT + idx] = out[NF_OUT + idx] / denom;
}

extern "C" void kernel_launch(void* const* d_in, const int* in_sizes, int n_in,
                              void* d_out, int out_size, void* d_ws, size_t ws_size,
                              hipStream_t stream) {
    const float* xyz = (const float*)d_in[0];
    const float* feats = (const float*)d_in[1];
    const float* sc = (const float*)d_in[2];
    float* out = (float*)d_out;
    float* ws = (float*)d_ws;

    hipMemsetAsync(ws, 0, (size_t)HDR_F * sizeof(float), stream);
    prep_kernel<<<BB, 256, 0, stream>>>(xyz, sc, ws);

    for (int it = 0; it < ITERS - 1; it++) {
        assign_kernel<false><<<dim3(64, BB), 256, 0, stream>>>(
            xyz, sc, (const float4*)(ws + it * SLICE_F),
            ws + (it + 1) * SLICE_F, out);
    }
    assign_kernel<true><<<dim3(64, BB), 256, 0, stream>>>(
        xyz, sc, (const float4*)(ws + (ITERS - 1) * SLICE_F),
        ws + ITERS * SLICE_F, out);

    final_kernel<<<BB, KK, 0, stream>>>(ws, out);

    if (ws_size >= WS_NEED_BYTES) {
        nf_mfma2<<<dim3(JPARTS, BB), 256, 0, stream>>>(out, feats, ws + PART_OFF);
        nf_reduce<<<256, 256, 0, stream>>>(ws, out);
    } else {
        hipMemsetAsync(out + NF_OUT, 0, (size_t)BB * KK * DD * sizeof(float), stream);
        nf_compute_atomic<<<dim3(JPARTS, BB), 256, 0, stream>>>(out, feats, out + NF_OUT);
        nf_finalize<<<256, 256, 0, stream>>>(ws, out);
    }
}

// Round 11
// 322.856 us; speedup vs baseline: 1.7692x; 1.1105x over previous
//
#include <hip/hip_runtime.h>
#include <hip/hip_bf16.h>

typedef __attribute__((ext_vector_type(8))) short short8;
typedef __attribute__((ext_vector_type(4))) float f32x4;

#define BB 8
#define NN 32768
#define KK 128
#define DD 64
#define TAU 1.0f
#define ITERS 10
#define EPSV 1e-8f
#define JPARTS 128

// ---- d_out layout (floats) ----
#define G_SZ   ((size_t)BB * NN * KK)
#define PI_OFF (G_SZ)
#define XY_OFF (PI_OFF + (size_t)BB * KK)
#define NF_OUT (XY_OFF + (size_t)BB * KK * 3)

// ---- d_ws layout (floats) ----  (round-7 layout)
#define SLICE_F (BB * KK * 4)                  // 4096
#define SS_OFF  ((ITERS + 1) * SLICE_F)        // 45056
#define HDR_F   (SS_OFF + 16)                  // 45072
#define PART_OFF HDR_F
#define PART_F  ((size_t)JPARTS * BB * KK * DD)
#define WS_NEED_BYTES  ((PART_OFF + PART_F) * 4)

__device__ __forceinline__ unsigned pk2(float a, float b) {
    __hip_bfloat162 h = __float22bfloat162_rn(make_float2(a, b));
    unsigned u; __builtin_memcpy(&u, &h, 4); return u;
}
__device__ __forceinline__ float rdl(float v, int l) {
    return __int_as_float(__builtin_amdgcn_readlane(__float_as_int(v), l));
}
// x += dpp(x) — LLVM atomic-optimizer wave64 sum step (VALU pipe, no LDS).
// CTRL/RMASK must be compile-time constants (builtin requirement).
template <int CTRL, int RMASK>
__device__ __forceinline__ float dpp_add(float x) {
    int t = __builtin_amdgcn_update_dpp(0, __float_as_int(x), CTRL, RMASK, 0xf, false);
    return x + __int_as_float(t);
}
// full-wave sum -> scalar (valid in lane 63, broadcast via readlane)
__device__ __forceinline__ float wave_sum64(float x) {
    x = dpp_add<0x111, 0xf>(x);   // row_shr:1
    x = dpp_add<0x112, 0xf>(x);   // row_shr:2
    x = dpp_add<0x114, 0xf>(x);   // row_shr:4
    x = dpp_add<0x118, 0xf>(x);   // row_shr:8
    x = dpp_add<0x142, 0xa>(x);   // row_bcast:15 -> rows 1,3
    x = dpp_add<0x143, 0xc>(x);   // row_bcast:31 -> rows 2,3
    return rdl(x, 63);
}

// ================= prep: s_sum + initial centers as acc slice 0 =================
__global__ __launch_bounds__(256) void prep_kernel(const float* __restrict__ xyz,
                                                   const float* __restrict__ sc,
                                                   float* __restrict__ ws) {
    int b = blockIdx.x, tid = threadIdx.x, wave = tid >> 6, lane = tid & 63;
    const float* S = sc + (size_t)b * NN;
    float sum = 0.f;
    for (int i = tid; i < NN; i += 256) sum += S[i];
    #pragma unroll
    for (int m = 1; m <= 32; m <<= 1) sum += __shfl_xor(sum, m, 64);
    __shared__ float red[4];
    if (lane == 0) red[wave] = sum;
    __syncthreads();
    if (tid == 0) ws[SS_OFF + b] = red[0] + red[1] + red[2] + red[3] + EPSV;
    if (tid < KK) {
        const float* X = xyz + (size_t)b * 3 * NN;
        int i0 = tid * (NN / KK);
        ((float4*)ws)[b * KK + tid] =
            make_float4(X[i0], X[NN + i0], X[2 * NN + i0], 1.0f);
    }
}

// ============ assign: SINGLE-pass, k-per-lane, DPP wave-sum softmax =============
// grid (64, B), block 256 (4 waves), 512 points/block.
// Lane owns clusters lane, lane+64 (centers in regs from accIn). Wave w sweeps
// its 128 points; per point: 1 ds_read_b128 broadcast + 2 exp + DPP row-sum.
template <bool LAST>
__global__ __launch_bounds__(256) void assign_kernel(
    const float* __restrict__ xyz, const float* __restrict__ sc,
    const float4* __restrict__ accIn,   // slice it
    float* __restrict__ accOut,         // slice it+1 (pre-zeroed)
    float* __restrict__ gamma_out)
{
    __shared__ float4 wLds[512];     // {x,y,z,s}
    __shared__ float  accW[4][512];

    const int b = blockIdx.y, blk = blockIdx.x;
    const int tid = threadIdx.x, wave = tid >> 6, lane = tid & 63;

    const float* X = xyz + (size_t)b * 3 * NN;
    const float* S = sc + (size_t)b * NN;

    const int n = blk * 512 + tid;
    wLds[tid]       = make_float4(X[n], X[NN + n], X[2 * NN + n], S[n]);
    wLds[tid + 256] = make_float4(X[n + 256], X[NN + n + 256], X[2 * NN + n + 256], S[n + 256]);

    // per-lane transformed centers (clusters lane, lane+64) from accumulator
    float4 a0 = accIn[b * KK + lane];
    float4 a1 = accIn[b * KK + 64 + lane];
    float d0 = a0.w + EPSV, d1 = a1.w + EPSV;
    float cx0 = a0.x / d0, cy0 = a0.y / d0, cz0 = a0.z / d0;
    float cx1 = a1.x / d1, cy1 = a1.y / d1, cz1 = a1.z / d1;
    const float4 c0 = make_float4(2.f * cx0 / TAU, 2.f * cy0 / TAU, 2.f * cz0 / TAU,
                                  -(cx0 * cx0 + cy0 * cy0 + cz0 * cz0) / TAU);
    const float4 c1 = make_float4(2.f * cx1 / TAU, 2.f * cy1 / TAU, 2.f * cz1 / TAU,
                                  -(cx1 * cx1 + cy1 * cy1 + cz1 * cz1) / TAU);
    __syncthreads();

    float ax0 = 0, ay0 = 0, az0 = 0, aw0 = 0;
    float ax1 = 0, ay1 = 0, az1 = 0, aw1 = 0;
    float* grow = gamma_out + ((size_t)b * NN + blk * 512 + (wave << 7)) * KK + lane;

    #pragma unroll 4
    for (int j = 0; j < 128; ++j) {
        float4 P = wLds[(wave << 7) | j];   // wave-uniform broadcast read
        float e0 = __expf(fmaf(P.x, c0.x, fmaf(P.y, c0.y, fmaf(P.z, c0.z, c0.w))));
        float e1 = __expf(fmaf(P.x, c1.x, fmaf(P.y, c1.y, fmaf(P.z, c1.z, c1.w))));
        float l = wave_sum64(e0 + e1);      // softmax denom, VALU-pipe DPP
        float w = __fdividef(P.w, l);
        float g0 = e0 * w, g1 = e1 * w;
        if (LAST) {
            grow[(size_t)j * KK] = g0;
            grow[(size_t)j * KK + 64] = g1;
        }
        ax0 = fmaf(g0, P.x, ax0); ay0 = fmaf(g0, P.y, ay0);
        az0 = fmaf(g0, P.z, az0); aw0 += g0;
        ax1 = fmaf(g1, P.x, ax1); ay1 = fmaf(g1, P.y, ay1);
        az1 = fmaf(g1, P.z, az1); aw1 += g1;
    }

    ((float4*)accW[wave])[lane]      = make_float4(ax0, ay0, az0, aw0);
    ((float4*)accW[wave])[lane + 64] = make_float4(ax1, ay1, az1, aw1);
    __syncthreads();
    float v0 = accW[0][tid]       + accW[1][tid]       + accW[2][tid]       + accW[3][tid];
    float v1 = accW[0][tid + 256] + accW[1][tid + 256] + accW[2][tid + 256] + accW[3][tid + 256];
    float* ag = accOut + b * (KK * 4);
    atomicAdd(ag + tid, v0);
    atomicAdd(ag + tid + 256, v1);
}

// ================= final: node_xyz + pi from slice ITERS =================
__global__ void final_kernel(const float* __restrict__ ws, float* __restrict__ out) {
    int b = blockIdx.x, k = threadIdx.x;
    float4 a = ((const float4*)(ws + ITERS * SLICE_F))[b * KK + k];
    float denom = a.w + EPSV;
    float* oxyz = out + XY_OFF + (size_t)(b * KK + k) * 3;
    oxyz[0] = a.x / denom; oxyz[1] = a.y / denom; oxyz[2] = a.z / denom;
    out[PI_OFF + b * KK + k] = a.w / ws[SS_OFF + b];
}

// ====== nf_mfma2: partial nf[k][d] via 16x16x32 bf16 MFMA (round-6 proven) =====
__global__ __launch_bounds__(256) void nf_mfma2(const float* __restrict__ gamma,
                                                const float* __restrict__ feats,
                                                float* __restrict__ dst) {
    __shared__ unsigned short gT[KK * 40];   // [k][pitch 40 bf16], 10240 B
    const int b = blockIdx.y, part = blockIdx.x;
    const int tid = threadIdx.x, wave = tid >> 6, lane = tid & 63;
    const int r = lane & 15, hi = lane >> 4;
    const int p = tid & 15, q0 = tid >> 4;

    f32x4 acc[2][4];
    #pragma unroll
    for (int kt = 0; kt < 2; kt++)
        #pragma unroll
        for (int dt = 0; dt < 4; dt++) acc[kt][dt] = (f32x4){0.f, 0.f, 0.f, 0.f};

    const float* gb = gamma + (size_t)b * NN * KK + (size_t)part * 256 * KK;
    const float* fb = feats + (size_t)b * DD * NN;
    const int n0 = part * 256;

    for (int ch = 0; ch < 8; ++ch) {
        const float* gr0 = gb + (size_t)(ch * 32 + 2 * p) * KK;
        const float* gr1 = gr0 + KK;
        unsigned* rowd = (unsigned*)gT;
        #pragma unroll
        for (int s = 0; s < 2; ++s) {
            int q = q0 + 16 * s;
            float4 x = *(const float4*)(gr0 + 4 * q);
            float4 y = *(const float4*)(gr1 + 4 * q);
            rowd[(4 * q + 0) * 20 + p] = pk2(x.x, y.x);
            rowd[(4 * q + 1) * 20 + p] = pk2(x.y, y.y);
            rowd[(4 * q + 2) * 20 + p] = pk2(x.z, y.z);
            rowd[(4 * q + 3) * 20 + p] = pk2(x.w, y.w);
        }
        __syncthreads();

        const unsigned short* a0p = gT + (wave * 32 + r) * 40 + hi * 8;
        short8 a0 = *(const short8*)a0p;
        short8 a1 = *(const short8*)(a0p + 16 * 40);
        const int nn = n0 + ch * 32 + hi * 8;
        #pragma unroll
        for (int dt = 0; dt < 4; ++dt) {
            const float* fr = fb + (size_t)(dt * 16 + r) * NN + nn;
            float4 x = *(const float4*)fr;
            float4 y = *(const float4*)(fr + 4);
            union { unsigned u[4]; short8 s; } bu;
            bu.u[0] = pk2(x.x, x.y); bu.u[1] = pk2(x.z, x.w);
            bu.u[2] = pk2(y.x, y.y); bu.u[3] = pk2(y.z, y.w);
            acc[0][dt] = __builtin_amdgcn_mfma_f32_16x16x32_bf16(a0, bu.s, acc[0][dt], 0, 0, 0);
            acc[1][dt] = __builtin_amdgcn_mfma_f32_16x16x32_bf16(a1, bu.s, acc[1][dt], 0, 0, 0);
        }
        __syncthreads();
    }

    float* pdst = dst + ((size_t)(b * JPARTS + part)) * (KK * DD) + (size_t)(wave * 32) * DD;
    #pragma unroll
    for (int kt = 0; kt < 2; kt++)
        #pragma unroll
        for (int dt = 0; dt < 4; dt++)
            #pragma unroll
            for (int rr = 0; rr < 4; rr++)
                pdst[(kt * 16 + hi * 4 + rr) * DD + dt * 16 + r] = acc[kt][dt][rr];
}

// ====== fallback f32 nf_compute (round-4 proven), atomic variant ======
__global__ __launch_bounds__(256) void nf_compute_atomic(const float* __restrict__ gamma,
                                                         const float* __restrict__ feats,
                                                         float* __restrict__ dst) {
    __shared__ float gLds[32 * 128];
    __shared__ float fLds[64 * 33];
    const int b = blockIdx.y, part = blockIdx.x, tid = threadIdx.x;
    const int kq = (tid & 15) * 8, dg = (tid >> 4) * 4;
    float acc[8][4];
    #pragma unroll
    for (int i = 0; i < 8; i++)
        #pragma unroll
        for (int u = 0; u < 4; u++) acc[i][u] = 0.f;
    const float* gb = gamma + (size_t)b * NN * KK + (size_t)part * (NN / JPARTS) * KK;
    const float* fb = feats + (size_t)b * DD * NN + part * (NN / JPARTS);
    for (int ch = 0; ch < (NN / JPARTS) / 32; ++ch) {
        const float4* gs = (const float4*)(gb + (size_t)ch * 32 * KK);
        #pragma unroll
        for (int i = 0; i < 4; i++) ((float4*)gLds)[tid + i * 256] = gs[tid + i * 256];
        #pragma unroll
        for (int i = 0; i < 2; i++) {
            int idx = tid + i * 256;
            int d = idx >> 3, c4 = (idx & 7) * 4;
            float4 fv = *(const float4*)(fb + (size_t)d * NN + ch * 32 + c4);
            float* fr = &fLds[d * 33 + c4];
            fr[0] = fv.x; fr[1] = fv.y; fr[2] = fv.z; fr[3] = fv.w;
        }
        __syncthreads();
        #pragma unroll 4
        for (int nl = 0; nl < 32; ++nl) {
            float4 g0 = *(const float4*)&gLds[nl * 128 + kq];
            float4 g1 = *(const float4*)&gLds[nl * 128 + kq + 4];
            float fv[4];
            #pragma unroll
            for (int u = 0; u < 4; u++) fv[u] = fLds[(dg + u) * 33 + nl];
            float gk[8] = {g0.x, g0.y, g0.z, g0.w, g1.x, g1.y, g1.z, g1.w};
            #pragma unroll
            for (int i = 0; i < 8; i++)
                #pragma unroll
                for (int u = 0; u < 4; u++)
                    acc[i][u] = fmaf(gk[i], fv[u], acc[i][u]);
        }
        __syncthreads();
    }
    float* nf = dst + (size_t)b * KK * DD;
    #pragma unroll
    for (int i = 0; i < 8; i++)
        #pragma unroll
        for (int u = 0; u < 4; u++)
            atomicAdd(&nf[(kq + i) * DD + dg + u], acc[i][u]);
}

// ====== nf_reduce: sum JPARTS partials, divide by denom, write out ======
__global__ __launch_bounds__(256) void nf_reduce(const float* __restrict__ ws,
                                                 float* __restrict__ out) {
    int idx = blockIdx.x * 256 + threadIdx.x;
    int b = idx >> 13, e = idx & 8191;
    const float* p = ws + PART_OFF + (size_t)b * JPARTS * (KK * DD) + e;
    float sum = 0.f;
    #pragma unroll 8
    for (int j = 0; j < JPARTS; ++j) sum += p[(size_t)j * (KK * DD)];
    int k = e >> 6;
    float denom = ws[ITERS * SLICE_F + (b * KK + k) * 4 + 3] + EPSV;
    out[NF_OUT + idx] = sum / denom;
}

__global__ __launch_bounds__(256) void nf_finalize(const float* __restrict__ ws,
                                                   float* __restrict__ out) {
    int idx = blockIdx.x * 256 + threadIdx.x;
    int bk = idx / DD;
    float denom = ws[ITERS * SLICE_F + bk * 4 + 3] + EPSV;
    out[NF_OUT + idx] = out[NF_OUT + idx] / denom;
}

extern "C" void kernel_launch(void* const* d_in, const int* in_sizes, int n_in,
                              void* d_out, int out_size, void* d_ws, size_t ws_size,
                              hipStream_t stream) {
    const float* xyz = (const float*)d_in[0];
    const float* feats = (const float*)d_in[1];
    const float* sc = (const float*)d_in[2];
    float* out = (float*)d_out;
    float* ws = (float*)d_ws;

    hipMemsetAsync(ws, 0, (size_t)HDR_F * sizeof(float), stream);
    prep_kernel<<<BB, 256, 0, stream>>>(xyz, sc, ws);

    for (int it = 0; it < ITERS - 1; it++) {
        assign_kernel<false><<<dim3(64, BB), 256, 0, stream>>>(
            xyz, sc, (const float4*)(ws + it * SLICE_F),
            ws + (it + 1) * SLICE_F, out);
    }
    assign_kernel<true><<<dim3(64, BB), 256, 0, stream>>>(
        xyz, sc, (const float4*)(ws + (ITERS - 1) * SLICE_F),
        ws + ITERS * SLICE_F, out);

    final_kernel<<<BB, KK, 0, stream>>>(ws, out);

    if (ws_size >= WS_NEED_BYTES) {
        nf_mfma2<<<dim3(JPARTS, BB), 256, 0, stream>>>(out, feats, ws + PART_OFF);
        nf_reduce<<<256, 256, 0, stream>>>(ws, out);
    } else {
        hipMemsetAsync(out + NF_OUT, 0, (size_t)BB * KK * DD * sizeof(float), stream);
        nf_compute_atomic<<<dim3(JPARTS, BB), 256, 0, stream>>>(out, feats, out + NF_OUT);
        nf_finalize<<<256, 256, 0, stream>>>(ws, out);
    }
}

// Round 12
// 294.814 us; speedup vs baseline: 1.9374x; 1.0951x over previous
//
#include <hip/hip_runtime.h>
#include <hip/hip_bf16.h>

typedef __attribute__((ext_vector_type(8))) short short8;
typedef __attribute__((ext_vector_type(4))) float f32x4;

#define BB 8
#define NN 32768
#define KK 128
#define DD 64
#define TAU 1.0f
#define ITERS 10
#define EPSV 1e-8f
#define JPARTS 128

// ---- d_out layout (floats) ----
#define G_SZ   ((size_t)BB * NN * KK)
#define PI_OFF (G_SZ)
#define XY_OFF (PI_OFF + (size_t)BB * KK)
#define NF_OUT (XY_OFF + (size_t)BB * KK * 3)

// ---- d_ws layout (floats) ----
#define SLICE_F (BB * KK * 4)                  // 4096
#define HDR_F   ((ITERS + 1) * SLICE_F)        // acc slices 0..10 (slice 0 unused)

__device__ __forceinline__ unsigned pk2(float a, float b) {
    __hip_bfloat162 h = __float22bfloat162_rn(make_float2(a, b));
    unsigned u; __builtin_memcpy(&u, &h, 4); return u;
}

// ============ assign: round-7 two-pass softmax (proven fastest) =================
// grid (64, B), block 256 (4 waves), 512 points/block.
// FIRST: centers = xyz[:, k*(N/K)] directly. Else: centers from acc slice.
template <bool FIRST, bool LAST>
__global__ __launch_bounds__(256) void assign_kernel(
    const float* __restrict__ xyz, const float* __restrict__ sc,
    const float4* __restrict__ accIn,   // slice it (unused if FIRST)
    float* __restrict__ accOut,         // slice it+1 (pre-zeroed)
    float* __restrict__ gamma_out)
{
    __shared__ float4 cLds[KK];      // {2cx,2cy,2cz,-|c|^2}/tau
    __shared__ float4 wLds[512];     // {x,y,z, s/l}
    __shared__ float  accW[4][512];

    const int b = blockIdx.y, blk = blockIdx.x;
    const int tid = threadIdx.x, wave = tid >> 6, lane = tid & 63;

    const float* X = xyz + (size_t)b * 3 * NN;
    const float* S = sc + (size_t)b * NN;

    const int n = blk * 512 + tid;
    const float px0 = X[n],       py0 = X[NN + n],       pz0 = X[2 * NN + n],       ps0 = S[n];
    const float px1 = X[n + 256], py1 = X[NN + n + 256], pz1 = X[2 * NN + n + 256], ps1 = S[n + 256];

    if (tid < KK) {
        float cx, cy, cz;
        if (FIRST) {
            int i0 = tid * (NN / KK);
            cx = X[i0]; cy = X[NN + i0]; cz = X[2 * NN + i0];
        } else {
            float4 a = accIn[b * KK + tid];
            float denom = a.w + EPSV;
            cx = a.x / denom; cy = a.y / denom; cz = a.z / denom;
        }
        cLds[tid] = make_float4(2.f * cx / TAU, 2.f * cy / TAU, 2.f * cz / TAU,
                                -(cx * cx + cy * cy + cz * cz) / TAU);
    }
    __syncthreads();

    // pass 1: softmax denominators for 2 points/thread (one cLds read pair
    // serves both points; 4 independent exp chains).
    float l0a = 0.f, l0b = 0.f, l1a = 0.f, l1b = 0.f;
    #pragma unroll 8
    for (int k = 0; k < KK; k += 2) {
        float4 ca = cLds[k], cb = cLds[k + 1];
        l0a += __expf(fmaf(px0, ca.x, fmaf(py0, ca.y, fmaf(pz0, ca.z, ca.w))));
        l1a += __expf(fmaf(px1, ca.x, fmaf(py1, ca.y, fmaf(pz1, ca.z, ca.w))));
        l0b += __expf(fmaf(px0, cb.x, fmaf(py0, cb.y, fmaf(pz0, cb.z, cb.w))));
        l1b += __expf(fmaf(px1, cb.x, fmaf(py1, cb.y, fmaf(pz1, cb.z, cb.w))));
    }
    wLds[tid]       = make_float4(px0, py0, pz0, ps0 / (l0a + l0b));
    wLds[tid + 256] = make_float4(px1, py1, pz1, ps1 / (l1a + l1b));
    __syncthreads();

    // pass 2: lane owns clusters lane, lane+64; wave sweeps its 128 points.
    const float4 c0 = cLds[lane];
    const float4 c1 = cLds[lane + 64];
    float ax0 = 0, ay0 = 0, az0 = 0, aw0 = 0;
    float ax1 = 0, ay1 = 0, az1 = 0, aw1 = 0;
    float* grow = gamma_out + ((size_t)b * NN + blk * 512 + (wave << 7)) * KK + lane;

    #pragma unroll 4
    for (int j = 0; j < 128; ++j) {
        float4 P = wLds[(wave << 7) | j];   // wave-uniform broadcast
        float g0 = __expf(fmaf(P.x, c0.x, fmaf(P.y, c0.y, fmaf(P.z, c0.z, c0.w)))) * P.w;
        float g1 = __expf(fmaf(P.x, c1.x, fmaf(P.y, c1.y, fmaf(P.z, c1.z, c1.w)))) * P.w;
        if (LAST) {
            grow[(size_t)j * KK] = g0;
            grow[(size_t)j * KK + 64] = g1;
        }
        ax0 = fmaf(g0, P.x, ax0); ay0 = fmaf(g0, P.y, ay0);
        az0 = fmaf(g0, P.z, az0); aw0 += g0;
        ax1 = fmaf(g1, P.x, ax1); ay1 = fmaf(g1, P.y, ay1);
        az1 = fmaf(g1, P.z, az1); aw1 += g1;
    }

    ((float4*)accW[wave])[lane]      = make_float4(ax0, ay0, az0, aw0);
    ((float4*)accW[wave])[lane + 64] = make_float4(ax1, ay1, az1, aw1);
    __syncthreads();
    float v0 = accW[0][tid]       + accW[1][tid]       + accW[2][tid]       + accW[3][tid];
    float v1 = accW[0][tid + 256] + accW[1][tid + 256] + accW[2][tid + 256] + accW[3][tid + 256];
    float* ag = accOut + b * (KK * 4);
    atomicAdd(ag + tid, v0);
    atomicAdd(ag + tid + 256, v1);
}

// ========= final: s_sum (inline) + node_xyz + pi from slice ITERS ==============
__global__ __launch_bounds__(256) void final_kernel(const float* __restrict__ sc,
                                                    const float* __restrict__ ws,
                                                    float* __restrict__ out) {
    int b = blockIdx.x, tid = threadIdx.x, wave = tid >> 6, lane = tid & 63;
    const float* S = sc + (size_t)b * NN;
    float sum = 0.f;
    for (int i = tid; i < NN; i += 256) sum += S[i];
    #pragma unroll
    for (int m = 1; m <= 32; m <<= 1) sum += __shfl_xor(sum, m, 64);
    __shared__ float red[4];
    if (lane == 0) red[wave] = sum;
    __syncthreads();
    if (tid < KK) {
        float ssum = red[0] + red[1] + red[2] + red[3] + EPSV;
        float4 a = ((const float4*)(ws + ITERS * SLICE_F))[b * KK + tid];
        float denom = a.w + EPSV;
        float* oxyz = out + XY_OFF + (size_t)(b * KK + tid) * 3;
        oxyz[0] = a.x / denom; oxyz[1] = a.y / denom; oxyz[2] = a.z / denom;
        out[PI_OFF + b * KK + tid] = a.w / ssum;
    }
}

// ====== nf_mfma2: nf[k][d] via 16x16x32 bf16 MFMA, atomic accumulate ======
// grid (JPARTS, B), block 256 (4 waves). Reads gamma f32 [n][k] from d_out,
// stages transposed bf16 gT[k][n] in LDS (pitch 20 dw -> 2-way banks, free).
// Wave w owns k-rows [32w, 32w+32), all 64 d. Epilogue: atomicAdd into out.
__global__ __launch_bounds__(256) void nf_mfma2(const float* __restrict__ gamma,
                                                const float* __restrict__ feats,
                                                float* __restrict__ nf_acc) {
    __shared__ unsigned short gT[KK * 40];   // [k][pitch 40 bf16], 10240 B
    const int b = blockIdx.y, part = blockIdx.x;
    const int tid = threadIdx.x, wave = tid >> 6, lane = tid & 63;
    const int r = lane & 15, hi = lane >> 4;
    const int p = tid & 15, q0 = tid >> 4;

    f32x4 acc[2][4];
    #pragma unroll
    for (int kt = 0; kt < 2; kt++)
        #pragma unroll
        for (int dt = 0; dt < 4; dt++) acc[kt][dt] = (f32x4){0.f, 0.f, 0.f, 0.f};

    const float* gb = gamma + (size_t)b * NN * KK + (size_t)part * 256 * KK;
    const float* fb = feats + (size_t)b * DD * NN;
    const int n0 = part * 256;

    for (int ch = 0; ch < 8; ++ch) {
        const float* gr0 = gb + (size_t)(ch * 32 + 2 * p) * KK;
        const float* gr1 = gr0 + KK;
        unsigned* rowd = (unsigned*)gT;
        #pragma unroll
        for (int s = 0; s < 2; ++s) {
            int q = q0 + 16 * s;
            float4 x = *(const float4*)(gr0 + 4 * q);
            float4 y = *(const float4*)(gr1 + 4 * q);
            rowd[(4 * q + 0) * 20 + p] = pk2(x.x, y.x);
            rowd[(4 * q + 1) * 20 + p] = pk2(x.y, y.y);
            rowd[(4 * q + 2) * 20 + p] = pk2(x.z, y.z);
            rowd[(4 * q + 3) * 20 + p] = pk2(x.w, y.w);
        }
        __syncthreads();

        const unsigned short* a0p = gT + (wave * 32 + r) * 40 + hi * 8;
        short8 a0 = *(const short8*)a0p;
        short8 a1 = *(const short8*)(a0p + 16 * 40);
        const int nn = n0 + ch * 32 + hi * 8;
        #pragma unroll
        for (int dt = 0; dt < 4; ++dt) {
            const float* fr = fb + (size_t)(dt * 16 + r) * NN + nn;
            float4 x = *(const float4*)fr;
            float4 y = *(const float4*)(fr + 4);
            union { unsigned u[4]; short8 s; } bu;
            bu.u[0] = pk2(x.x, x.y); bu.u[1] = pk2(x.z, x.w);
            bu.u[2] = pk2(y.x, y.y); bu.u[3] = pk2(y.z, y.w);
            acc[0][dt] = __builtin_amdgcn_mfma_f32_16x16x32_bf16(a0, bu.s, acc[0][dt], 0, 0, 0);
            acc[1][dt] = __builtin_amdgcn_mfma_f32_16x16x32_bf16(a1, bu.s, acc[1][dt], 0, 0, 0);
        }
        __syncthreads();
    }

    float* nf = nf_acc + (size_t)b * KK * DD + (size_t)(wave * 32) * DD;
    #pragma unroll
    for (int kt = 0; kt < 2; kt++)
        #pragma unroll
        for (int dt = 0; dt < 4; dt++)
            #pragma unroll
            for (int rr = 0; rr < 4; rr++)
                atomicAdd(&nf[(kt * 16 + hi * 4 + rr) * DD + dt * 16 + r],
                          acc[kt][dt][rr]);
}

// ====== nf_finalize: divide accumulated nf by denom, in place ======
__global__ __launch_bounds__(256) void nf_finalize(const float* __restrict__ ws,
                                                   float* __restrict__ out) {
    int idx = blockIdx.x * 256 + threadIdx.x;   // [0, B*K*D)
    int bk = idx / DD;
    float denom = ws[ITERS * SLICE_F + bk * 4 + 3] + EPSV;
    out[NF_OUT + idx] = out[NF_OUT + idx] / denom;
}

extern "C" void kernel_launch(void* const* d_in, const int* in_sizes, int n_in,
                              void* d_out, int out_size, void* d_ws, size_t ws_size,
                              hipStream_t stream) {
    const float* xyz = (const float*)d_in[0];
    const float* feats = (const float*)d_in[1];
    const float* sc = (const float*)d_in[2];
    float* out = (float*)d_out;
    float* ws = (float*)d_ws;

    hipMemsetAsync(ws, 0, (size_t)HDR_F * sizeof(float), stream);
    hipMemsetAsync(out + NF_OUT, 0, (size_t)BB * KK * DD * sizeof(float), stream);

    assign_kernel<true, false><<<dim3(64, BB), 256, 0, stream>>>(
        xyz, sc, nullptr, ws + SLICE_F, out);
    for (int it = 1; it < ITERS - 1; it++) {
        assign_kernel<false, false><<<dim3(64, BB), 256, 0, stream>>>(
            xyz, sc, (const float4*)(ws + it * SLICE_F),
            ws + (it + 1) * SLICE_F, out);
    }
    assign_kernel<false, true><<<dim3(64, BB), 256, 0, stream>>>(
        xyz, sc, (const float4*)(ws + (ITERS - 1) * SLICE_F),
        ws + ITERS * SLICE_F, out);

    final_kernel<<<BB, 256, 0, stream>>>(sc, ws, out);
    nf_mfma2<<<dim3(JPARTS, BB), 256, 0, stream>>>(out, feats, out + NF_OUT);
    nf_finalize<<<256, 256, 0, stream>>>(ws, out);
}